// Round 5
// baseline (578.625 us; speedup 1.0000x reference)
//
#include <hip/hip_runtime.h>
#include <stdint.h>

#define IN_DIM 256
#define HID 128
#define BKT_BITS 6
#define BKT_SZ 64
#define MAXBKT 2048

typedef __attribute__((ext_vector_type(8))) short short8v;   // 8 bf16 (4 VGPRs)
typedef __attribute__((ext_vector_type(4))) float f32x4;     // MFMA acc

// ---------------- bf16 helpers ----------------------------------------------
__device__ __forceinline__ unsigned short f2bf(float f) {
    unsigned u = __float_as_uint(f);
    unsigned rnd = 0x7FFFu + ((u >> 16) & 1u);
    return (unsigned short)((u + rnd) >> 16);
}
__device__ __forceinline__ float bflo(unsigned v) { return __uint_as_float(v << 16); }
__device__ __forceinline__ float bfhi(unsigned v) { return __uint_as_float(v & 0xFFFF0000u); }

// ---------------- threefry2x32 dropout (JAX partitionable path) -------------
__device__ __forceinline__ unsigned rotl32(unsigned x, int r) {
    return (x << r) | (x >> (32 - r));
}
__device__ __forceinline__ float dropout_scale(unsigned idx) {
    const unsigned ks0 = 0u, ks1 = 42u, ks2 = 0x1BD11BF0u;
    unsigned x0 = 0u + ks0;
    unsigned x1 = idx + ks1;
#define TF_ROUND(r) { x0 += x1; x1 = rotl32(x1, r); x1 ^= x0; }
    TF_ROUND(13) TF_ROUND(15) TF_ROUND(26) TF_ROUND(6)
    x0 += ks1; x1 += ks2 + 1u;
    TF_ROUND(17) TF_ROUND(29) TF_ROUND(16) TF_ROUND(24)
    x0 += ks2; x1 += ks0 + 2u;
    TF_ROUND(13) TF_ROUND(15) TF_ROUND(26) TF_ROUND(6)
    x0 += ks0; x1 += ks1 + 3u;
    TF_ROUND(17) TF_ROUND(29) TF_ROUND(16) TF_ROUND(24)
    x0 += ks1; x1 += ks2 + 4u;
    TF_ROUND(13) TF_ROUND(15) TF_ROUND(26) TF_ROUND(6)
    x0 += ks2; x1 += ks0 + 5u;
#undef TF_ROUND
    unsigned bits = x0 ^ x1;
    float u = __uint_as_float(0x3F800000u | (bits >> 9)) - 1.0f;
    return (u < 0.9f) ? (1.0f / 0.9f) : 0.0f;
}

// ---------------- bucketed CSR build ----------------------------------------
// k1: per-block LDS sub-histogram of bucket ids -> global bhist
__global__ __launch_bounds__(256) void bucket_hist(const int* __restrict__ dst,
                                                   int* __restrict__ bhist,
                                                   int E, int nbkt) {
    __shared__ int lh[MAXBKT];
    for (int i = threadIdx.x; i < nbkt; i += 256) lh[i] = 0;
    __syncthreads();
    int stride = gridDim.x * blockDim.x;
    for (int i = blockIdx.x * blockDim.x + threadIdx.x; i < E; i += stride)
        atomicAdd(&lh[dst[i] >> BKT_BITS], 1);
    __syncthreads();
    for (int i = threadIdx.x; i < nbkt; i += 256) {
        int v = lh[i];
        if (v) atomicAdd(&bhist[i], v);
    }
}

// k2: single-block exclusive scan of bucket counts (nbkt <= 2048)
__global__ __launch_bounds__(256) void bucket_scan(const int* __restrict__ bhist,
                                                   int* __restrict__ bbase,
                                                   int* __restrict__ bcursor,
                                                   int nbkt, int E) {
    __shared__ int lds[256];
    int t = threadIdx.x;
    int base = t * 8;
    int v[8];
    int s = 0;
    for (int j = 0; j < 8; ++j) {
        int x = (base + j < nbkt) ? bhist[base + j] : 0;
        v[j] = s;          // exclusive prefix within thread
        s += x;
    }
    lds[t] = s;
    __syncthreads();
    for (int d = 1; d < 256; d <<= 1) {
        int val = lds[t];
        int add = (t >= d) ? lds[t - d] : 0;
        __syncthreads();
        lds[t] = val + add;
        __syncthreads();
    }
    int excl = lds[t] - s;
    for (int j = 0; j < 8; ++j) {
        int idx = base + j;
        if (idx < nbkt) {
            int b0 = excl + v[j];
            bbase[idx] = b0;
            bcursor[idx] = b0;
        }
    }
    if (t == 255) bbase[nbkt] = E;
}

// k3: scatter packed (src<<6 | dst&63) into bucket-contiguous regions
__global__ __launch_bounds__(256) void bucket_scatter(const int* __restrict__ src,
                                                      const int* __restrict__ dst,
                                                      int* __restrict__ bcursor,
                                                      unsigned* __restrict__ packed, int E) {
    int stride = gridDim.x * blockDim.x;
    for (int e = blockIdx.x * blockDim.x + threadIdx.x; e < E; e += stride) {
        int d = dst[e];
        int pos = atomicAdd(&bcursor[d >> BKT_BITS], 1);
        packed[pos] = ((unsigned)src[e] << BKT_BITS) | (unsigned)(d & (BKT_SZ - 1));
    }
}

// k4: per-bucket finalize: per-node offsets, dinv, ssrc (L2-local scatter)
__global__ __launch_bounds__(256) void bucket_finalize(const unsigned* __restrict__ packed,
                                                       const int* __restrict__ bbase,
                                                       int* __restrict__ ssrc,
                                                       int* __restrict__ offs,
                                                       float* __restrict__ dinv, int N) {
    __shared__ int hist[BKT_SZ];
    __shared__ int cur[BKT_SZ];
    int b = blockIdx.x;
    int t = threadIdx.x;
    int beg = bbase[b], end = bbase[b + 1];
    if (t < BKT_SZ) hist[t] = 0;
    __syncthreads();
    for (int i = beg + t; i < end; i += 256)
        atomicAdd(&hist[packed[i] & (BKT_SZ - 1)], 1);
    __syncthreads();
    if (t < BKT_SZ) cur[t] = hist[t];
    __syncthreads();
    for (int d = 1; d < BKT_SZ; d <<= 1) {
        int val = 0;
        if (t < BKT_SZ) { val = cur[t]; if (t >= d) val += cur[t - d]; }
        __syncthreads();
        if (t < BKT_SZ) cur[t] = val;
        __syncthreads();
    }
    if (t < BKT_SZ) {
        int node = b * BKT_SZ + t;
        int excl = cur[t] - hist[t];
        if (node < N) {
            offs[node] = beg + excl;
            dinv[node] = rsqrtf((float)(hist[t] + 1));
        }
        cur[t] = excl;   // becomes per-node cursor
    }
    __syncthreads();
    for (int i = beg + t; i < end; i += 256) {
        unsigned p = packed[i];
        int dl = (int)(p & (BKT_SZ - 1));
        int pos = atomicAdd(&cur[dl], 1);
        ssrc[beg + pos] = (int)(p >> BKT_BITS);
    }
}

// ---------------- weight fp32 -> bf16 ---------------------------------------
__global__ void cvt_w(const float* __restrict__ W, unsigned short* __restrict__ Wb, int n) {
    int i = blockIdx.x * blockDim.x + threadIdx.x;
    if (i < n) Wb[i] = f2bf(W[i]);
}

// ---------------- bf16 MFMA GEMM: C[M x 128] = A[M x K] @ W[128 x K]^T ------
#define WP 264   // padded W row stride (ushorts) -> 2-way banks (free)
#define AP 40    // padded A row stride (ushorts)
template <int A_BF16>
__global__ __launch_bounds__(256) void gemm_mfma(const void* __restrict__ Ap,
                                                 const unsigned short* __restrict__ Wb,
                                                 unsigned short* __restrict__ C,
                                                 int M, int K) {
    __shared__ unsigned short Wlds[128 * WP];
    __shared__ unsigned short Alds[64 * AP];
    const int t = threadIdx.x;
    const int bm = blockIdx.x * 64;

    const int kc = K >> 3;
    for (int c = t; c < 128 * kc; c += 256) {
        int row = c / kc, ko = c % kc;
        short8v w = *(const short8v*)(Wb + (size_t)row * K + ko * 8);
        *(short8v*)(&Wlds[row * WP + ko * 8]) = w;
    }

    const int w = t >> 6, l = t & 63;
    const int lr = l & 15, lk = l >> 4;
    const int sr = t >> 2, sc = t & 3;

    f32x4 acc[8] = {};

    for (int kb = 0; kb < K; kb += 32) {
        if (A_BF16) {
            short8v v = {};
            if (bm + sr < M)
                v = *(const short8v*)((const unsigned short*)Ap + (size_t)(bm + sr) * K + kb + sc * 8);
            *(short8v*)(&Alds[sr * AP + sc * 8]) = v;
        } else {
            short8v u = {};
            if (bm + sr < M) {
                const float* arow = (const float*)Ap + (size_t)(bm + sr) * K + kb + sc * 8;
                float4 f0 = *(const float4*)(arow);
                float4 f1 = *(const float4*)(arow + 4);
                u[0] = (short)f2bf(f0.x); u[1] = (short)f2bf(f0.y);
                u[2] = (short)f2bf(f0.z); u[3] = (short)f2bf(f0.w);
                u[4] = (short)f2bf(f1.x); u[5] = (short)f2bf(f1.y);
                u[6] = (short)f2bf(f1.z); u[7] = (short)f2bf(f1.w);
            }
            *(short8v*)(&Alds[sr * AP + sc * 8]) = u;
        }
        __syncthreads();

        short8v a = *(const short8v*)(&Alds[(w * 16 + lr) * AP + lk * 8]);
#pragma unroll
        for (int cb = 0; cb < 8; ++cb) {
            short8v b = *(const short8v*)(&Wlds[(cb * 16 + lr) * WP + kb + lk * 8]);
            acc[cb] = __builtin_amdgcn_mfma_f32_16x16x32_bf16(a, b, acc[cb], 0, 0, 0);
        }
        __syncthreads();
    }

#pragma unroll
    for (int cb = 0; cb < 8; ++cb) {
#pragma unroll
        for (int j = 0; j < 4; ++j) {
            int row = bm + w * 16 + lk * 4 + j;
            int col = cb * 16 + lr;
            if (row < M) C[(size_t)row * 128 + col] = f2bf(acc[cb][j]);
        }
    }
}

// ---------------- CSR gather aggregation (bf16 h), fused epilogue -----------
// MODE 1: out(bf16) = dropout(relu(agg + b));  MODE 2: out(fp32) = agg + b
template <int MODE>
__global__ __launch_bounds__(256) void aggregate_csr(const unsigned* __restrict__ h,
                                                     const int* __restrict__ soff,
                                                     const int* __restrict__ ssrc,
                                                     const float* __restrict__ dinv,
                                                     const float* __restrict__ bias,
                                                     void* __restrict__ outp,
                                                     int N, int E) {
    int n = blockIdx.x * 4 + (threadIdx.x >> 6);
    if (n >= N) return;
    int lane = threadIdx.x & 63;
    int start = soff[n];
    int end = (n + 1 < N) ? soff[n + 1] : E;
    float dn = dinv[n];

    float ax = 0.f, ay = 0.f;
    int s_nxt = (start < end) ? ssrc[start] : 0;
    for (int i = start; i < end; ++i) {
        int s = s_nxt;
        if (i + 1 < end) s_nxt = ssrc[i + 1];
        float wgt = dinv[s];
        unsigned v = h[(size_t)s * 64 + lane];
        ax = fmaf(wgt, bflo(v), ax);
        ay = fmaf(wgt, bfhi(v), ay);
    }
    unsigned hv = h[(size_t)n * 64 + lane];
    ax = (ax + dn * bflo(hv)) * dn;
    ay = (ay + dn * bfhi(hv)) * dn;
    float2 bv = ((const float2*)bias)[lane];
    ax += bv.x;
    ay += bv.y;
    if (MODE == 1) {
        unsigned idx = (unsigned)n * 128u + (unsigned)lane * 2u;
        ax = fmaxf(ax, 0.f) * dropout_scale(idx);
        ay = fmaxf(ay, 0.f) * dropout_scale(idx + 1u);
        ((unsigned*)outp)[(size_t)n * 64 + lane] =
            (unsigned)f2bf(ax) | ((unsigned)f2bf(ay) << 16);
    } else {
        ((float2*)outp)[(size_t)n * 64 + lane] = make_float2(ax, ay);
    }
}

// ---------------- launcher ---------------------------------------------------
extern "C" void kernel_launch(void* const* d_in, const int* in_sizes, int n_in,
                              void* d_out, int out_size, void* d_ws, size_t ws_size,
                              hipStream_t stream) {
    const float* X  = (const float*)d_in[0];
    const int*   ei = (const int*)d_in[1];
    const float* W1 = (const float*)d_in[2];
    const float* b1 = (const float*)d_in[3];
    const float* W2 = (const float*)d_in[4];
    const float* b2 = (const float*)d_in[5];
    float* out = (float*)d_out;

    const int N = in_sizes[0] / IN_DIM;  // 100000
    const int E = in_sizes[1] / 2;       // 1600000
    const int* src = ei;
    const int* dst = ei + E;
    const int total = N * HID;
    const size_t N4 = (size_t)N * 4;
    const size_t tot2 = (size_t)total * 2;
    const int NBKT = (N + BKT_SZ - 1) >> BKT_BITS;   // 1563 (<= MAXBKT)

    char* ws = (char*)d_ws;
    size_t off = 0;
    unsigned short* hA = (unsigned short*)(ws + off); off += tot2;
    unsigned short* hB = (unsigned short*)(ws + off); off += tot2;
    float* dinv = (float*)(ws + off); off += N4;
    int* offs   = (int*)(ws + off); off += N4;
    int* bhist  = (int*)(ws + off); off += (size_t)MAXBKT * 4;
    int* bbase  = (int*)(ws + off); off += (size_t)(MAXBKT + 1) * 4;
    int* bcur   = (int*)(ws + off); off += (size_t)MAXBKT * 4;
    unsigned* packed = (unsigned*)(ws + off); off += (size_t)E * 4;
    int* ssrc   = (int*)(ws + off); off += (size_t)E * 4;
    unsigned short* Wb1 = (unsigned short*)(ws + off); off += (size_t)HID * IN_DIM * 2;
    unsigned short* Wb2 = (unsigned short*)(ws + off);

    // CSR build (bucketed) + weight conversion
    hipMemsetAsync(bhist, 0, (size_t)NBKT * 4, stream);
    cvt_w<<<(HID * IN_DIM + 255) / 256, 256, 0, stream>>>(W1, Wb1, HID * IN_DIM);
    cvt_w<<<(HID * HID + 255) / 256, 256, 0, stream>>>(W2, Wb2, HID * HID);
    bucket_hist<<<256, 256, 0, stream>>>(dst, bhist, E, NBKT);
    bucket_scan<<<1, 256, 0, stream>>>(bhist, bbase, bcur, NBKT, E);
    bucket_scatter<<<2048, 256, 0, stream>>>(src, dst, bcur, packed, E);
    bucket_finalize<<<NBKT, 256, 0, stream>>>(packed, bbase, ssrc, offs, dinv, N);

    // layer 1
    gemm_mfma<0><<<(N + 63) / 64, 256, 0, stream>>>(X, Wb1, hA, N, IN_DIM);
    aggregate_csr<1><<<(N + 3) / 4, 256, 0, stream>>>((const unsigned*)hA, offs, ssrc,
                                                      dinv, b1, hB, N, E);
    // layer 2
    gemm_mfma<1><<<(N + 63) / 64, 256, 0, stream>>>(hB, Wb2, hA, N, HID);
    aggregate_csr<2><<<(N + 3) / 4, 256, 0, stream>>>((const unsigned*)hA, offs, ssrc,
                                                      dinv, b2, out, N, E);
}

// Round 6
// 362.930 us; speedup vs baseline: 1.5943x; 1.5943x over previous
//
#include <hip/hip_runtime.h>
#include <stdint.h>

#define IN_DIM 256
#define HID 128
#define BKT_BITS 6
#define BKT_SZ 64
#define MAXBKT 2048
#define NB_BLK 256   // partitions for contention-free scatter

typedef __attribute__((ext_vector_type(8))) short short8v;   // 8 bf16 (4 VGPRs)
typedef __attribute__((ext_vector_type(4))) float f32x4;     // MFMA acc

// ---------------- bf16 helpers ----------------------------------------------
__device__ __forceinline__ unsigned short f2bf(float f) {
    unsigned u = __float_as_uint(f);
    unsigned rnd = 0x7FFFu + ((u >> 16) & 1u);
    return (unsigned short)((u + rnd) >> 16);
}
__device__ __forceinline__ float bflo(unsigned v) { return __uint_as_float(v << 16); }
__device__ __forceinline__ float bfhi(unsigned v) { return __uint_as_float(v & 0xFFFF0000u); }

// ---------------- threefry2x32 dropout (JAX partitionable path) -------------
__device__ __forceinline__ unsigned rotl32(unsigned x, int r) {
    return (x << r) | (x >> (32 - r));
}
__device__ __forceinline__ float dropout_scale(unsigned idx) {
    const unsigned ks0 = 0u, ks1 = 42u, ks2 = 0x1BD11BF0u;
    unsigned x0 = 0u + ks0;
    unsigned x1 = idx + ks1;
#define TF_ROUND(r) { x0 += x1; x1 = rotl32(x1, r); x1 ^= x0; }
    TF_ROUND(13) TF_ROUND(15) TF_ROUND(26) TF_ROUND(6)
    x0 += ks1; x1 += ks2 + 1u;
    TF_ROUND(17) TF_ROUND(29) TF_ROUND(16) TF_ROUND(24)
    x0 += ks2; x1 += ks0 + 2u;
    TF_ROUND(13) TF_ROUND(15) TF_ROUND(26) TF_ROUND(6)
    x0 += ks0; x1 += ks1 + 3u;
    TF_ROUND(17) TF_ROUND(29) TF_ROUND(16) TF_ROUND(24)
    x0 += ks1; x1 += ks2 + 4u;
    TF_ROUND(13) TF_ROUND(15) TF_ROUND(26) TF_ROUND(6)
    x0 += ks2; x1 += ks0 + 5u;
#undef TF_ROUND
    unsigned bits = x0 ^ x1;
    float u = __uint_as_float(0x3F800000u | (bits >> 9)) - 1.0f;
    return (u < 0.9f) ? (1.0f / 0.9f) : 0.0f;
}

// ---------------- partitioned bucket CSR build ------------------------------
// A: per-partition LDS histogram -> counts[bkt*NB + blk] (bkt-major, scan order)
__global__ __launch_bounds__(256) void part_count(const int* __restrict__ dst,
                                                  int* __restrict__ counts,
                                                  int E, int nbkt, int per) {
    __shared__ int lh[MAXBKT];
    for (int i = threadIdx.x; i < nbkt; i += 256) lh[i] = 0;
    __syncthreads();
    int blk = blockIdx.x;
    int beg = blk * per, end = min(E, beg + per);
    for (int i = beg + threadIdx.x; i < end; i += 256)
        atomicAdd(&lh[dst[i] >> BKT_BITS], 1);
    __syncthreads();
    for (int b = threadIdx.x; b < nbkt; b += 256)
        counts[b * NB_BLK + blk] = lh[b];
}

// B: 3-phase exclusive scan over M = nbkt*NB elements (2048/block)
__global__ __launch_bounds__(256) void scan2_local(const int* __restrict__ in,
                                                   int* __restrict__ out,
                                                   int* __restrict__ bsum, int M) {
    __shared__ int lds[256];
    int t = threadIdx.x;
    int base = blockIdx.x * 2048 + t * 8;
    int x[8], v[8];
    if (base + 7 < M) {
        int4 a = *(const int4*)(in + base);
        int4 b = *(const int4*)(in + base + 4);
        x[0] = a.x; x[1] = a.y; x[2] = a.z; x[3] = a.w;
        x[4] = b.x; x[5] = b.y; x[6] = b.z; x[7] = b.w;
    } else {
        for (int j = 0; j < 8; ++j) x[j] = (base + j < M) ? in[base + j] : 0;
    }
    int s = 0;
    for (int j = 0; j < 8; ++j) { v[j] = s; s += x[j]; }
    lds[t] = s;
    __syncthreads();
    for (int d = 1; d < 256; d <<= 1) {
        int val = lds[t];
        int add = (t >= d) ? lds[t - d] : 0;
        __syncthreads();
        lds[t] = val + add;
        __syncthreads();
    }
    int excl = lds[t] - s;
    for (int j = 0; j < 8; ++j)
        if (base + j < M) out[base + j] = excl + v[j];
    if (t == 255) bsum[blockIdx.x] = lds[255];
}
__global__ __launch_bounds__(256) void scan2_bsums(int* __restrict__ bsum, int nb) {
    __shared__ int lds[256];
    int t = threadIdx.x;
    int orig = (t < nb) ? bsum[t] : 0;
    lds[t] = orig;
    __syncthreads();
    for (int d = 1; d < 256; d <<= 1) {
        int val = lds[t];
        int add = (t >= d) ? lds[t - d] : 0;
        __syncthreads();
        lds[t] = val + add;
        __syncthreads();
    }
    if (t < nb) bsum[t] = lds[t] - orig;
}
__global__ void scan2_add(int* __restrict__ out, const int* __restrict__ bsum, int M) {
    int i = blockIdx.x * blockDim.x + threadIdx.x;
    if (i < M) out[i] += bsum[i >> 11];
}

// C: scatter with private per-partition bases; LDS cursors only
__global__ __launch_bounds__(256) void part_scatter(const int* __restrict__ src,
                                                    const int* __restrict__ dst,
                                                    const int* __restrict__ cbase,
                                                    unsigned* __restrict__ packed,
                                                    int E, int nbkt, int per) {
    __shared__ int cur[MAXBKT];
    int blk = blockIdx.x;
    for (int b = threadIdx.x; b < nbkt; b += 256)
        cur[b] = cbase[b * NB_BLK + blk];
    __syncthreads();
    int beg = blk * per, end = min(E, beg + per);
    for (int i = beg + threadIdx.x; i < end; i += 256) {
        int d = dst[i];
        int pos = atomicAdd(&cur[d >> BKT_BITS], 1);
        packed[pos] = ((unsigned)src[i] << BKT_BITS) | (unsigned)(d & (BKT_SZ - 1));
    }
}

__global__ void extract_bbase(const int* __restrict__ cbase, int* __restrict__ bbase,
                              int nbkt, int E) {
    int b = blockIdx.x * blockDim.x + threadIdx.x;
    if (b < nbkt) bbase[b] = cbase[b * NB_BLK];
    if (b == nbkt) bbase[nbkt] = E;
}

// D: per-bucket finalize: per-node offsets, dinv, ssrc (L2-local scatter)
__global__ __launch_bounds__(256) void bucket_finalize(const unsigned* __restrict__ packed,
                                                       const int* __restrict__ bbase,
                                                       int* __restrict__ ssrc,
                                                       int* __restrict__ offs,
                                                       float* __restrict__ dinv, int N) {
    __shared__ int hist[BKT_SZ];
    __shared__ int cur[BKT_SZ];
    int b = blockIdx.x;
    int t = threadIdx.x;
    int beg = bbase[b], end = bbase[b + 1];
    if (t < BKT_SZ) hist[t] = 0;
    __syncthreads();
    for (int i = beg + t; i < end; i += 256)
        atomicAdd(&hist[packed[i] & (BKT_SZ - 1)], 1);
    __syncthreads();
    if (t < BKT_SZ) cur[t] = hist[t];
    __syncthreads();
    for (int d = 1; d < BKT_SZ; d <<= 1) {
        int val = 0;
        if (t < BKT_SZ) { val = cur[t]; if (t >= d) val += cur[t - d]; }
        __syncthreads();
        if (t < BKT_SZ) cur[t] = val;
        __syncthreads();
    }
    if (t < BKT_SZ) {
        int node = b * BKT_SZ + t;
        int excl = cur[t] - hist[t];
        if (node < N) {
            offs[node] = beg + excl;
            dinv[node] = rsqrtf((float)(hist[t] + 1));
        }
        cur[t] = excl;
    }
    __syncthreads();
    for (int i = beg + t; i < end; i += 256) {
        unsigned p = packed[i];
        int dl = (int)(p & (BKT_SZ - 1));
        int pos = atomicAdd(&cur[dl], 1);
        ssrc[beg + pos] = (int)(p >> BKT_BITS);
    }
}

// ---------------- weight fp32 -> bf16 ---------------------------------------
__global__ void cvt_w(const float* __restrict__ W, unsigned short* __restrict__ Wb, int n) {
    int i = blockIdx.x * blockDim.x + threadIdx.x;
    if (i < n) Wb[i] = f2bf(W[i]);
}

// ---------------- bf16 MFMA GEMM: C[M x 128] = A[M x K] @ W[128 x K]^T ------
#define WP 264   // padded W row stride (ushorts) -> 2-way banks (free)
#define AP 40    // padded A row stride (ushorts)
template <int A_BF16>
__global__ __launch_bounds__(256) void gemm_mfma(const void* __restrict__ Ap,
                                                 const unsigned short* __restrict__ Wb,
                                                 unsigned short* __restrict__ C,
                                                 int M, int K) {
    __shared__ unsigned short Wlds[128 * WP];
    __shared__ unsigned short Alds[64 * AP];
    const int t = threadIdx.x;
    const int bm = blockIdx.x * 64;

    const int kc = K >> 3;
    for (int c = t; c < 128 * kc; c += 256) {
        int row = c / kc, ko = c % kc;
        short8v w = *(const short8v*)(Wb + (size_t)row * K + ko * 8);
        *(short8v*)(&Wlds[row * WP + ko * 8]) = w;
    }

    const int w = t >> 6, l = t & 63;
    const int lr = l & 15, lk = l >> 4;
    const int sr = t >> 2, sc = t & 3;

    f32x4 acc[8] = {};

    for (int kb = 0; kb < K; kb += 32) {
        if (A_BF16) {
            short8v v = {};
            if (bm + sr < M)
                v = *(const short8v*)((const unsigned short*)Ap + (size_t)(bm + sr) * K + kb + sc * 8);
            *(short8v*)(&Alds[sr * AP + sc * 8]) = v;
        } else {
            short8v u = {};
            if (bm + sr < M) {
                const float* arow = (const float*)Ap + (size_t)(bm + sr) * K + kb + sc * 8;
                float4 f0 = *(const float4*)(arow);
                float4 f1 = *(const float4*)(arow + 4);
                u[0] = (short)f2bf(f0.x); u[1] = (short)f2bf(f0.y);
                u[2] = (short)f2bf(f0.z); u[3] = (short)f2bf(f0.w);
                u[4] = (short)f2bf(f1.x); u[5] = (short)f2bf(f1.y);
                u[6] = (short)f2bf(f1.z); u[7] = (short)f2bf(f1.w);
            }
            *(short8v*)(&Alds[sr * AP + sc * 8]) = u;
        }
        __syncthreads();

        short8v a = *(const short8v*)(&Alds[(w * 16 + lr) * AP + lk * 8]);
#pragma unroll
        for (int cb = 0; cb < 8; ++cb) {
            short8v b = *(const short8v*)(&Wlds[(cb * 16 + lr) * WP + kb + lk * 8]);
            acc[cb] = __builtin_amdgcn_mfma_f32_16x16x32_bf16(a, b, acc[cb], 0, 0, 0);
        }
        __syncthreads();
    }

#pragma unroll
    for (int cb = 0; cb < 8; ++cb) {
#pragma unroll
        for (int j = 0; j < 4; ++j) {
            int row = bm + w * 16 + lk * 4 + j;
            int col = cb * 16 + lr;
            if (row < M) C[(size_t)row * 128 + col] = f2bf(acc[cb][j]);
        }
    }
}

// ---------------- CSR gather aggregation (bf16 h), fused epilogue -----------
// MODE 1: out(bf16) = dropout(relu(agg + b));  MODE 2: out(fp32) = agg + b
template <int MODE>
__global__ __launch_bounds__(256) void aggregate_csr(const unsigned* __restrict__ h,
                                                     const int* __restrict__ soff,
                                                     const int* __restrict__ ssrc,
                                                     const float* __restrict__ dinv,
                                                     const float* __restrict__ bias,
                                                     void* __restrict__ outp,
                                                     int N, int E) {
    int n = blockIdx.x * 4 + (threadIdx.x >> 6);
    if (n >= N) return;
    int lane = threadIdx.x & 63;
    int start = soff[n];
    int end = (n + 1 < N) ? soff[n + 1] : E;
    float dn = dinv[n];

    float ax = 0.f, ay = 0.f;
    int s_nxt = (start < end) ? ssrc[start] : 0;
    for (int i = start; i < end; ++i) {
        int s = s_nxt;
        if (i + 1 < end) s_nxt = ssrc[i + 1];
        float wgt = dinv[s];
        unsigned v = h[(size_t)s * 64 + lane];
        ax = fmaf(wgt, bflo(v), ax);
        ay = fmaf(wgt, bfhi(v), ay);
    }
    unsigned hv = h[(size_t)n * 64 + lane];
    ax = (ax + dn * bflo(hv)) * dn;
    ay = (ay + dn * bfhi(hv)) * dn;
    float2 bv = ((const float2*)bias)[lane];
    ax += bv.x;
    ay += bv.y;
    if (MODE == 1) {
        unsigned idx = (unsigned)n * 128u + (unsigned)lane * 2u;
        ax = fmaxf(ax, 0.f) * dropout_scale(idx);
        ay = fmaxf(ay, 0.f) * dropout_scale(idx + 1u);
        ((unsigned*)outp)[(size_t)n * 64 + lane] =
            (unsigned)f2bf(ax) | ((unsigned)f2bf(ay) << 16);
    } else {
        ((float2*)outp)[(size_t)n * 64 + lane] = make_float2(ax, ay);
    }
}

// ---------------- launcher ---------------------------------------------------
extern "C" void kernel_launch(void* const* d_in, const int* in_sizes, int n_in,
                              void* d_out, int out_size, void* d_ws, size_t ws_size,
                              hipStream_t stream) {
    const float* X  = (const float*)d_in[0];
    const int*   ei = (const int*)d_in[1];
    const float* W1 = (const float*)d_in[2];
    const float* b1 = (const float*)d_in[3];
    const float* W2 = (const float*)d_in[4];
    const float* b2 = (const float*)d_in[5];
    float* out = (float*)d_out;

    const int N = in_sizes[0] / IN_DIM;  // 100000
    const int E = in_sizes[1] / 2;       // 1600000
    const int* src = ei;
    const int* dst = ei + E;
    const int total = N * HID;
    const size_t N4 = (size_t)N * 4;
    const size_t tot2 = (size_t)total * 2;
    const int NBKT = (N + BKT_SZ - 1) >> BKT_BITS;   // 1563 (<= MAXBKT)
    const int M = NBKT * NB_BLK;                     // counts matrix size
    const int per = (E + NB_BLK - 1) / NB_BLK;       // edges per partition
    const int snb = (M + 2047) / 2048;               // scan blocks (<=256)

    char* ws = (char*)d_ws;
    size_t off = 0;
    unsigned short* hA = (unsigned short*)(ws + off); off += tot2;
    unsigned short* hB = (unsigned short*)(ws + off); off += tot2;
    float* dinv = (float*)(ws + off); off += N4;
    int* offs   = (int*)(ws + off); off += N4;
    int* counts = (int*)(ws + off); off += (size_t)M * 4;
    int* cbase  = (int*)(ws + off); off += (size_t)M * 4;
    int* bsum   = (int*)(ws + off); off += 4096;
    int* bbase  = (int*)(ws + off); off += (size_t)(MAXBKT + 1) * 4;
    unsigned* packed = (unsigned*)(ws + off); off += (size_t)E * 4;
    int* ssrc   = (int*)(ws + off); off += (size_t)E * 4;
    unsigned short* Wb1 = (unsigned short*)(ws + off); off += (size_t)HID * IN_DIM * 2;
    unsigned short* Wb2 = (unsigned short*)(ws + off);

    // CSR build (partitioned, contention-free) + weight conversion
    cvt_w<<<(HID * IN_DIM + 255) / 256, 256, 0, stream>>>(W1, Wb1, HID * IN_DIM);
    cvt_w<<<(HID * HID + 255) / 256, 256, 0, stream>>>(W2, Wb2, HID * HID);
    part_count<<<NB_BLK, 256, 0, stream>>>(dst, counts, E, NBKT, per);
    scan2_local<<<snb, 256, 0, stream>>>(counts, cbase, bsum, M);
    scan2_bsums<<<1, 256, 0, stream>>>(bsum, snb);
    scan2_add<<<(M + 255) / 256, 256, 0, stream>>>(cbase, bsum, M);
    part_scatter<<<NB_BLK, 256, 0, stream>>>(src, dst, cbase, packed, E, NBKT, per);
    extract_bbase<<<(NBKT + 256) / 256, 256, 0, stream>>>(cbase, bbase, NBKT, E);
    bucket_finalize<<<NBKT, 256, 0, stream>>>(packed, bbase, ssrc, offs, dinv, N);

    // layer 1
    gemm_mfma<0><<<(N + 63) / 64, 256, 0, stream>>>(X, Wb1, hA, N, IN_DIM);
    aggregate_csr<1><<<(N + 3) / 4, 256, 0, stream>>>((const unsigned*)hA, offs, ssrc,
                                                      dinv, b1, hB, N, E);
    // layer 2
    gemm_mfma<1><<<(N + 63) / 64, 256, 0, stream>>>(hB, Wb2, hA, N, HID);
    aggregate_csr<2><<<(N + 3) / 4, 256, 0, stream>>>((const unsigned*)hA, offs, ssrc,
                                                      dinv, b2, out, N, E);
}

// Round 7
// 301.652 us; speedup vs baseline: 1.9182x; 1.2031x over previous
//
#include <hip/hip_runtime.h>
#include <stdint.h>

#define IN_DIM 256
#define HID 128
#define BKT_BITS 6
#define BKT_SZ 64
#define MAXBKT 2048
#define NB_BLK 256   // partitions for contention-free scatter

typedef __attribute__((ext_vector_type(8))) short short8v;   // 8 bf16 (4 VGPRs)
typedef __attribute__((ext_vector_type(4))) float f32x4;     // MFMA acc

// ---------------- bf16 helpers ----------------------------------------------
__device__ __forceinline__ unsigned short f2bf(float f) {
    unsigned u = __float_as_uint(f);
    unsigned rnd = 0x7FFFu + ((u >> 16) & 1u);
    return (unsigned short)((u + rnd) >> 16);
}
__device__ __forceinline__ float bflo(unsigned v) { return __uint_as_float(v << 16); }
__device__ __forceinline__ float bfhi(unsigned v) { return __uint_as_float(v & 0xFFFF0000u); }

// ---------------- threefry2x32 dropout (JAX partitionable path) -------------
__device__ __forceinline__ unsigned rotl32(unsigned x, int r) {
    return (x << r) | (x >> (32 - r));
}
__device__ __forceinline__ float dropout_scale(unsigned idx) {
    const unsigned ks0 = 0u, ks1 = 42u, ks2 = 0x1BD11BF0u;
    unsigned x0 = 0u + ks0;
    unsigned x1 = idx + ks1;
#define TF_ROUND(r) { x0 += x1; x1 = rotl32(x1, r); x1 ^= x0; }
    TF_ROUND(13) TF_ROUND(15) TF_ROUND(26) TF_ROUND(6)
    x0 += ks1; x1 += ks2 + 1u;
    TF_ROUND(17) TF_ROUND(29) TF_ROUND(16) TF_ROUND(24)
    x0 += ks2; x1 += ks0 + 2u;
    TF_ROUND(13) TF_ROUND(15) TF_ROUND(26) TF_ROUND(6)
    x0 += ks0; x1 += ks1 + 3u;
    TF_ROUND(17) TF_ROUND(29) TF_ROUND(16) TF_ROUND(24)
    x0 += ks1; x1 += ks2 + 4u;
    TF_ROUND(13) TF_ROUND(15) TF_ROUND(26) TF_ROUND(6)
    x0 += ks2; x1 += ks0 + 5u;
#undef TF_ROUND
    unsigned bits = x0 ^ x1;
    float u = __uint_as_float(0x3F800000u | (bits >> 9)) - 1.0f;
    return (u < 0.9f) ? (1.0f / 0.9f) : 0.0f;
}

// ---------------- partitioned bucket CSR build ------------------------------
__global__ __launch_bounds__(256) void part_count(const int* __restrict__ dst,
                                                  int* __restrict__ counts,
                                                  int E, int nbkt, int per) {
    __shared__ int lh[MAXBKT];
    for (int i = threadIdx.x; i < nbkt; i += 256) lh[i] = 0;
    __syncthreads();
    int blk = blockIdx.x;
    int beg = blk * per, end = min(E, beg + per);
    for (int i = beg + threadIdx.x; i < end; i += 256)
        atomicAdd(&lh[dst[i] >> BKT_BITS], 1);
    __syncthreads();
    for (int b = threadIdx.x; b < nbkt; b += 256)
        counts[b * NB_BLK + blk] = lh[b];
}

__global__ __launch_bounds__(256) void scan2_local(const int* __restrict__ in,
                                                   int* __restrict__ out,
                                                   int* __restrict__ bsum, int M) {
    __shared__ int lds[256];
    int t = threadIdx.x;
    int base = blockIdx.x * 2048 + t * 8;
    int x[8], v[8];
    if (base + 7 < M) {
        int4 a = *(const int4*)(in + base);
        int4 b = *(const int4*)(in + base + 4);
        x[0] = a.x; x[1] = a.y; x[2] = a.z; x[3] = a.w;
        x[4] = b.x; x[5] = b.y; x[6] = b.z; x[7] = b.w;
    } else {
        for (int j = 0; j < 8; ++j) x[j] = (base + j < M) ? in[base + j] : 0;
    }
    int s = 0;
    for (int j = 0; j < 8; ++j) { v[j] = s; s += x[j]; }
    lds[t] = s;
    __syncthreads();
    for (int d = 1; d < 256; d <<= 1) {
        int val = lds[t];
        int add = (t >= d) ? lds[t - d] : 0;
        __syncthreads();
        lds[t] = val + add;
        __syncthreads();
    }
    int excl = lds[t] - s;
    for (int j = 0; j < 8; ++j)
        if (base + j < M) out[base + j] = excl + v[j];
    if (t == 255) bsum[blockIdx.x] = lds[255];
}
__global__ __launch_bounds__(256) void scan2_bsums(int* __restrict__ bsum, int nb) {
    __shared__ int lds[256];
    int t = threadIdx.x;
    int orig = (t < nb) ? bsum[t] : 0;
    lds[t] = orig;
    __syncthreads();
    for (int d = 1; d < 256; d <<= 1) {
        int val = lds[t];
        int add = (t >= d) ? lds[t - d] : 0;
        __syncthreads();
        lds[t] = val + add;
        __syncthreads();
    }
    if (t < nb) bsum[t] = lds[t] - orig;
}
__global__ void scan2_add(int* __restrict__ out, const int* __restrict__ bsum, int M) {
    int i = blockIdx.x * blockDim.x + threadIdx.x;
    if (i < M) out[i] += bsum[i >> 11];
}

__global__ __launch_bounds__(256) void part_scatter(const int* __restrict__ src,
                                                    const int* __restrict__ dst,
                                                    const int* __restrict__ cbase,
                                                    unsigned* __restrict__ packed,
                                                    int E, int nbkt, int per) {
    __shared__ int cur[MAXBKT];
    int blk = blockIdx.x;
    for (int b = threadIdx.x; b < nbkt; b += 256)
        cur[b] = cbase[b * NB_BLK + blk];
    __syncthreads();
    int beg = blk * per, end = min(E, beg + per);
    for (int i = beg + threadIdx.x; i < end; i += 256) {
        int d = dst[i];
        int pos = atomicAdd(&cur[d >> BKT_BITS], 1);
        packed[pos] = ((unsigned)src[i] << BKT_BITS) | (unsigned)(d & (BKT_SZ - 1));
    }
}

__global__ void extract_bbase(const int* __restrict__ cbase, int* __restrict__ bbase,
                              int nbkt, int E) {
    int b = blockIdx.x * blockDim.x + threadIdx.x;
    if (b < nbkt) bbase[b] = cbase[b * NB_BLK];
    if (b == nbkt) bbase[nbkt] = E;
}

__global__ __launch_bounds__(256) void bucket_finalize(const unsigned* __restrict__ packed,
                                                       const int* __restrict__ bbase,
                                                       int* __restrict__ ssrc,
                                                       int* __restrict__ offs,
                                                       float* __restrict__ dinv, int N) {
    __shared__ int hist[BKT_SZ];
    __shared__ int cur[BKT_SZ];
    int b = blockIdx.x;
    int t = threadIdx.x;
    int beg = bbase[b], end = bbase[b + 1];
    if (t < BKT_SZ) hist[t] = 0;
    __syncthreads();
    for (int i = beg + t; i < end; i += 256)
        atomicAdd(&hist[packed[i] & (BKT_SZ - 1)], 1);
    __syncthreads();
    if (t < BKT_SZ) cur[t] = hist[t];
    __syncthreads();
    for (int d = 1; d < BKT_SZ; d <<= 1) {
        int val = 0;
        if (t < BKT_SZ) { val = cur[t]; if (t >= d) val += cur[t - d]; }
        __syncthreads();
        if (t < BKT_SZ) cur[t] = val;
        __syncthreads();
    }
    if (t < BKT_SZ) {
        int node = b * BKT_SZ + t;
        int excl = cur[t] - hist[t];
        if (node < N) {
            offs[node] = beg + excl;
            dinv[node] = rsqrtf((float)(hist[t] + 1));
        }
        cur[t] = excl;
    }
    __syncthreads();
    for (int i = beg + t; i < end; i += 256) {
        unsigned p = packed[i];
        int dl = (int)(p & (BKT_SZ - 1));
        int pos = atomicAdd(&cur[dl], 1);
        ssrc[beg + pos] = (int)(p >> BKT_BITS);
    }
}

// ---------------- weight fp32 -> bf16 ---------------------------------------
__global__ void cvt_w(const float* __restrict__ W, unsigned short* __restrict__ Wb, int n) {
    int i = blockIdx.x * blockDim.x + threadIdx.x;
    if (i < n) Wb[i] = f2bf(W[i]);
}

// ---------------- bf16 MFMA GEMM: C[M x 128] = A[M x K] @ W[128 x K]^T ------
#define WP 264
#define AP 40
template <int A_BF16>
__global__ __launch_bounds__(256) void gemm_mfma(const void* __restrict__ Ap,
                                                 const unsigned short* __restrict__ Wb,
                                                 unsigned short* __restrict__ C,
                                                 int M, int K) {
    __shared__ unsigned short Wlds[128 * WP];
    __shared__ unsigned short Alds[64 * AP];
    const int t = threadIdx.x;
    const int bm = blockIdx.x * 64;

    const int kc = K >> 3;
    for (int c = t; c < 128 * kc; c += 256) {
        int row = c / kc, ko = c % kc;
        short8v w = *(const short8v*)(Wb + (size_t)row * K + ko * 8);
        *(short8v*)(&Wlds[row * WP + ko * 8]) = w;
    }

    const int w = t >> 6, l = t & 63;
    const int lr = l & 15, lk = l >> 4;
    const int sr = t >> 2, sc = t & 3;

    f32x4 acc[8] = {};

    for (int kb = 0; kb < K; kb += 32) {
        if (A_BF16) {
            short8v v = {};
            if (bm + sr < M)
                v = *(const short8v*)((const unsigned short*)Ap + (size_t)(bm + sr) * K + kb + sc * 8);
            *(short8v*)(&Alds[sr * AP + sc * 8]) = v;
        } else {
            short8v u = {};
            if (bm + sr < M) {
                const float* arow = (const float*)Ap + (size_t)(bm + sr) * K + kb + sc * 8;
                float4 f0 = *(const float4*)(arow);
                float4 f1 = *(const float4*)(arow + 4);
                u[0] = (short)f2bf(f0.x); u[1] = (short)f2bf(f0.y);
                u[2] = (short)f2bf(f0.z); u[3] = (short)f2bf(f0.w);
                u[4] = (short)f2bf(f1.x); u[5] = (short)f2bf(f1.y);
                u[6] = (short)f2bf(f1.z); u[7] = (short)f2bf(f1.w);
            }
            *(short8v*)(&Alds[sr * AP + sc * 8]) = u;
        }
        __syncthreads();

        short8v a = *(const short8v*)(&Alds[(w * 16 + lr) * AP + lk * 8]);
#pragma unroll
        for (int cb = 0; cb < 8; ++cb) {
            short8v b = *(const short8v*)(&Wlds[(cb * 16 + lr) * WP + kb + lk * 8]);
            acc[cb] = __builtin_amdgcn_mfma_f32_16x16x32_bf16(a, b, acc[cb], 0, 0, 0);
        }
        __syncthreads();
    }

#pragma unroll
    for (int cb = 0; cb < 8; ++cb) {
#pragma unroll
        for (int j = 0; j < 4; ++j) {
            int row = bm + w * 16 + lk * 4 + j;
            int col = cb * 16 + lr;
            if (row < M) C[(size_t)row * 128 + col] = f2bf(acc[cb][j]);
        }
    }
}

// ---------------- CSR gather aggregation: 4 edges / wave-iteration ----------
// 16 lanes per edge, dwordx4 per lane (16 B x 16 lanes = 256 B row).
// group g = lane>>4 handles edges start+i+g; butterfly-combine at the end.
// MODE 1: out(bf16) = dropout(relu(agg + b));  MODE 2: out(fp32) = agg + b
template <int MODE>
__global__ __launch_bounds__(256) void aggregate_csr(const unsigned* __restrict__ h,
                                                     const int* __restrict__ soff,
                                                     const int* __restrict__ ssrc,
                                                     const float* __restrict__ dinv,
                                                     const float* __restrict__ bias,
                                                     void* __restrict__ outp,
                                                     int N, int E) {
    int n = blockIdx.x * 4 + (threadIdx.x >> 6);
    if (n >= N) return;
    const int lane = threadIdx.x & 63;
    const int g = lane >> 4;      // edge group 0..3
    const int f0 = lane & 15;     // 16B chunk within the 256B row
    int start = soff[n];
    int end = (n + 1 < N) ? soff[n + 1] : E;
    float dn = dinv[n];

    float a0 = 0.f, a1 = 0.f, a2 = 0.f, a3 = 0.f,
          a4 = 0.f, a5 = 0.f, a6 = 0.f, a7 = 0.f;

    for (int i = start; i < end; i += 4) {
        int ig = i + g;
        int s = n;
        float wgt = 0.f;
        if (ig < end) { s = ssrc[ig]; wgt = dinv[s]; }
        uint4 v = *(const uint4*)(h + (size_t)s * 64 + f0 * 4);
        a0 = fmaf(wgt, bflo(v.x), a0);
        a1 = fmaf(wgt, bfhi(v.x), a1);
        a2 = fmaf(wgt, bflo(v.y), a2);
        a3 = fmaf(wgt, bfhi(v.y), a3);
        a4 = fmaf(wgt, bflo(v.z), a4);
        a5 = fmaf(wgt, bfhi(v.z), a5);
        a6 = fmaf(wgt, bflo(v.w), a6);
        a7 = fmaf(wgt, bfhi(v.w), a7);
    }

    // combine the 4 edge groups (lanes xor 16, 32); full sums land in all lanes
    a0 += __shfl_xor(a0, 16, 64); a0 += __shfl_xor(a0, 32, 64);
    a1 += __shfl_xor(a1, 16, 64); a1 += __shfl_xor(a1, 32, 64);
    a2 += __shfl_xor(a2, 16, 64); a2 += __shfl_xor(a2, 32, 64);
    a3 += __shfl_xor(a3, 16, 64); a3 += __shfl_xor(a3, 32, 64);
    a4 += __shfl_xor(a4, 16, 64); a4 += __shfl_xor(a4, 32, 64);
    a5 += __shfl_xor(a5, 16, 64); a5 += __shfl_xor(a5, 32, 64);
    a6 += __shfl_xor(a6, 16, 64); a6 += __shfl_xor(a6, 32, 64);
    a7 += __shfl_xor(a7, 16, 64); a7 += __shfl_xor(a7, 32, 64);

    // each group takes its 2-feature slice: f = f0*8 + g*2 + {0,1}
    uint4 hv = *(const uint4*)(h + (size_t)n * 64 + f0 * 4);
    unsigned hvg = (g == 0) ? hv.x : (g == 1) ? hv.y : (g == 2) ? hv.z : hv.w;
    float sx, sy;
    if (g == 0)      { sx = a0; sy = a1; }
    else if (g == 1) { sx = a2; sy = a3; }
    else if (g == 2) { sx = a4; sy = a5; }
    else             { sx = a6; sy = a7; }

    float ax = (sx + dn * bflo(hvg)) * dn;
    float ay = (sy + dn * bfhi(hvg)) * dn;
    float2 bv = ((const float2*)bias)[f0 * 4 + g];
    ax += bv.x;
    ay += bv.y;
    int fi = f0 * 8 + g * 2;
    if (MODE == 1) {
        unsigned idx = (unsigned)n * 128u + (unsigned)fi;
        ax = fmaxf(ax, 0.f) * dropout_scale(idx);
        ay = fmaxf(ay, 0.f) * dropout_scale(idx + 1u);
        ((unsigned*)outp)[(size_t)n * 64 + f0 * 4 + g] =
            (unsigned)f2bf(ax) | ((unsigned)f2bf(ay) << 16);
    } else {
        ((float2*)outp)[(size_t)n * 64 + f0 * 4 + g] = make_float2(ax, ay);
    }
}

// ---------------- launcher ---------------------------------------------------
extern "C" void kernel_launch(void* const* d_in, const int* in_sizes, int n_in,
                              void* d_out, int out_size, void* d_ws, size_t ws_size,
                              hipStream_t stream) {
    const float* X  = (const float*)d_in[0];
    const int*   ei = (const int*)d_in[1];
    const float* W1 = (const float*)d_in[2];
    const float* b1 = (const float*)d_in[3];
    const float* W2 = (const float*)d_in[4];
    const float* b2 = (const float*)d_in[5];
    float* out = (float*)d_out;

    const int N = in_sizes[0] / IN_DIM;  // 100000
    const int E = in_sizes[1] / 2;       // 1600000
    const int* src = ei;
    const int* dst = ei + E;
    const int total = N * HID;
    const size_t N4 = (size_t)N * 4;
    const size_t tot2 = (size_t)total * 2;
    const int NBKT = (N + BKT_SZ - 1) >> BKT_BITS;
    const int M = NBKT * NB_BLK;
    const int per = (E + NB_BLK - 1) / NB_BLK;
    const int snb = (M + 2047) / 2048;

    char* ws = (char*)d_ws;
    size_t off = 0;
    unsigned short* hA = (unsigned short*)(ws + off); off += tot2;
    unsigned short* hB = (unsigned short*)(ws + off); off += tot2;
    float* dinv = (float*)(ws + off); off += N4;
    int* offs   = (int*)(ws + off); off += N4;
    int* counts = (int*)(ws + off); off += (size_t)M * 4;
    int* cbase  = (int*)(ws + off); off += (size_t)M * 4;
    int* bsum   = (int*)(ws + off); off += 4096;
    int* bbase  = (int*)(ws + off); off += (size_t)(MAXBKT + 1) * 4;
    unsigned* packed = (unsigned*)(ws + off); off += (size_t)E * 4;
    int* ssrc   = (int*)(ws + off); off += (size_t)E * 4;
    unsigned short* Wb1 = (unsigned short*)(ws + off); off += (size_t)HID * IN_DIM * 2;
    unsigned short* Wb2 = (unsigned short*)(ws + off);

    // CSR build (partitioned, contention-free) + weight conversion
    cvt_w<<<(HID * IN_DIM + 255) / 256, 256, 0, stream>>>(W1, Wb1, HID * IN_DIM);
    cvt_w<<<(HID * HID + 255) / 256, 256, 0, stream>>>(W2, Wb2, HID * HID);
    part_count<<<NB_BLK, 256, 0, stream>>>(dst, counts, E, NBKT, per);
    scan2_local<<<snb, 256, 0, stream>>>(counts, cbase, bsum, M);
    scan2_bsums<<<1, 256, 0, stream>>>(bsum, snb);
    scan2_add<<<(M + 255) / 256, 256, 0, stream>>>(cbase, bsum, M);
    part_scatter<<<NB_BLK, 256, 0, stream>>>(src, dst, cbase, packed, E, NBKT, per);
    extract_bbase<<<(NBKT + 256) / 256, 256, 0, stream>>>(cbase, bbase, NBKT, E);
    bucket_finalize<<<NBKT, 256, 0, stream>>>(packed, bbase, ssrc, offs, dinv, N);

    // layer 1
    gemm_mfma<0><<<(N + 63) / 64, 256, 0, stream>>>(X, Wb1, hA, N, IN_DIM);
    aggregate_csr<1><<<(N + 3) / 4, 256, 0, stream>>>((const unsigned*)hA, offs, ssrc,
                                                      dinv, b1, hB, N, E);
    // layer 2
    gemm_mfma<1><<<(N + 63) / 64, 256, 0, stream>>>(hB, Wb2, hA, N, HID);
    aggregate_csr<2><<<(N + 3) / 4, 256, 0, stream>>>((const unsigned*)hA, offs, ssrc,
                                                      dinv, b2, out, N, E);
}